// Round 1
// baseline (76.059 us; speedup 1.0000x reference)
//
#include <hip/hip_runtime.h>

// Problem constants (from reference)
constexpr int B = 8;
constexpr int N = 8192;
constexpr int K = 2048;
constexpr int C = 64;
constexpr int NS = 32;            // N_SAMPLE
#define RAD2 0.0625f              // RADIUS^2, exact in fp32

// ---------------------------------------------------------------------------
// Kernel A: ball query (one wave per centroid) + grouped_pts output + idx to ws
// Reproduces: mask = d2 < r^2 with d2 = (|c|^2 + |p|^2) - 2*c.p  (fp32, no FMA
// contraction, sequential sum order — matches numpy/jax reference rounding).
// Selection = first NS in-radius point indices in ascending index order
// (stable argsort semantics); slots >= count padded with first hit (or 0).
// ---------------------------------------------------------------------------
__global__ __launch_bounds__(256) void ballquery_gp_kernel(
    const float* __restrict__ points,     // (B, N, 3)
    const float* __restrict__ centroids,  // (B, K, 3)
    float* __restrict__ gp_out,           // (B, 3, K, NS)
    int* __restrict__ idx_ws)             // (B, K, NS)
{
#pragma clang fp contract(off)
    const int wave = (blockIdx.x * blockDim.x + threadIdx.x) >> 6;
    const int lane = threadIdx.x & 63;
    if (wave >= B * K) return;
    const int b = wave / K;
    const int k = wave - b * K;

    const float* cptr = centroids + (size_t)(b * K + k) * 3;
    const float c0 = cptr[0], c1 = cptr[1], c2 = cptr[2];
    const float cc = (c0 * c0 + c1 * c1) + c2 * c2;

    const float* pbase = points + (size_t)b * N * 3;
    int* idxrow = idx_ws + (size_t)wave * NS;
    float* gpb = gp_out + ((size_t)b * 3 * K + k) * NS;  // + d*K*NS for dim d

    int count = 0;
    int idx0 = 0;  // first in-radius index (or 0 if none — matches order[0]=0)

    for (int base = 0; base < N; base += 64) {
        const int i = base + lane;
        const float p0 = pbase[i * 3 + 0];
        const float p1 = pbase[i * 3 + 1];
        const float p2 = pbase[i * 3 + 2];
        const float pp = (p0 * p0 + p1 * p1) + p2 * p2;
        const float cp = (c0 * p0 + c1 * p1) + c2 * p2;
        const float d2 = (cc + pp) - 2.0f * cp;
        const bool hit = d2 < RAD2;
        const unsigned long long m = __ballot(hit);
        if (hit) {
            const unsigned long long below = m & ((1ull << lane) - 1ull);
            const int pos = count + __popcll(below);
            if (pos < NS) {
                idxrow[pos] = i;
                gpb[0 * K * NS + pos] = (p0 - c0) * 4.0f;
                gpb[1 * K * NS + pos] = (p1 - c1) * 4.0f;
                gpb[2 * K * NS + pos] = (p2 - c2) * 4.0f;
            }
        }
        if (count == 0 && m != 0ull) idx0 = base + __builtin_ctzll(m);
        count += __popcll(m);
        if (count >= NS) break;  // wave-uniform
    }

    // Padding: slots [min(count,NS), NS) get idx0's point
    const int cnt = count < NS ? count : NS;
    if (lane >= cnt && lane < NS) {
        const float p0 = pbase[idx0 * 3 + 0];
        const float p1 = pbase[idx0 * 3 + 1];
        const float p2 = pbase[idx0 * 3 + 2];
        idxrow[lane] = idx0;
        gpb[0 * K * NS + lane] = (p0 - c0) * 4.0f;
        gpb[1 * K * NS + lane] = (p1 - c1) * 4.0f;
        gpb[2 * K * NS + lane] = (p2 - c2) * 4.0f;
    }
}

// ---------------------------------------------------------------------------
// Kernel B: new_feats[b,c,k,s] = features[b,c,idx[b,k,s]]
// One thread per 4 consecutive s (float4 store). Coalesced writes; gathered
// reads concentrate in the low-index prefix of each (b,c) row → cache hits.
// ---------------------------------------------------------------------------
__global__ __launch_bounds__(256) void gather_feats_kernel(
    const float* __restrict__ features,  // (B, C, N)
    const int* __restrict__ idx_ws,      // (B, K, NS)
    float* __restrict__ nf_out)          // (B, C, K, NS)
{
    const int t = blockIdx.x * blockDim.x + threadIdx.x;  // B*C*K*8 threads
    const int g = t & 7;                 // group of 4 along s
    const int kk = (t >> 3) & (K - 1);   // K = 2048
    const int bc = t >> 14;              // (b*C + c); K*8 = 2^14
    const int b = bc >> 6;               // C = 64

    const int4 iv = *reinterpret_cast<const int4*>(
        idx_ws + ((size_t)(b * K + kk) * NS) + g * 4);
    const float* frow = features + (size_t)bc * N;
    float4 v;
    v.x = frow[iv.x];
    v.y = frow[iv.y];
    v.z = frow[iv.z];
    v.w = frow[iv.w];
    *reinterpret_cast<float4*>(nf_out + (size_t)(bc * K + kk) * NS + g * 4) = v;
}

extern "C" void kernel_launch(void* const* d_in, const int* in_sizes, int n_in,
                              void* d_out, int out_size, void* d_ws, size_t ws_size,
                              hipStream_t stream) {
    const float* points    = (const float*)d_in[0];
    const float* centroids = (const float*)d_in[1];
    const float* features  = (const float*)d_in[2];
    float* out = (float*)d_out;

    float* gp_out = out;                              // B*3*K*NS = 1,572,864
    float* nf_out = out + (size_t)B * 3 * K * NS;     // B*C*K*NS = 33,554,432
    int* idx_ws = (int*)d_ws;                         // needs B*K*NS*4 = 2 MB

    // Kernel A: one wave per centroid -> B*K waves, 4 waves/block
    const int waves = B * K;                          // 16384
    const int blocksA = waves / 4;                    // 4096 blocks of 256
    hipLaunchKernelGGL(ballquery_gp_kernel, dim3(blocksA), dim3(256), 0, stream,
                       points, centroids, gp_out, idx_ws);

    // Kernel B: B*C*K*8 threads (each does 4 s-elements)
    const int totB = B * C * K * 8;                   // 8,388,608
    hipLaunchKernelGGL(gather_feats_kernel, dim3(totB / 256), dim3(256), 0, stream,
                       features, idx_ws, nf_out);
}

// Round 2
// 61.061 us; speedup vs baseline: 1.2456x; 1.2456x over previous
//
#include <hip/hip_runtime.h>

// Problem constants (from reference)
constexpr int B = 8;
constexpr int N = 8192;
constexpr int K = 2048;
constexpr int C = 64;
constexpr int NS = 32;            // N_SAMPLE
#define RAD2 0.0625f              // RADIUS^2, exact in fp32

// ---------------------------------------------------------------------------
// Kernel A: ball query (one wave per centroid) + grouped_pts output + idx to ws
// Reproduces: mask = d2 < r^2 with d2 = (|c|^2 + |p|^2) - 2*c.p  (fp32, no FMA
// contraction, sequential sum order — matches numpy/jax reference rounding).
// Selection = first NS in-radius point indices in ascending index order
// (stable argsort semantics); slots >= count padded with first hit (or 0).
// ---------------------------------------------------------------------------
__global__ __launch_bounds__(256) void ballquery_gp_kernel(
    const float* __restrict__ points,     // (B, N, 3)
    const float* __restrict__ centroids,  // (B, K, 3)
    float* __restrict__ gp_out,           // (B, 3, K, NS)
    int* __restrict__ idx_ws)             // (B, K, NS)
{
#pragma clang fp contract(off)
    const int wave = (blockIdx.x * blockDim.x + threadIdx.x) >> 6;
    const int lane = threadIdx.x & 63;
    if (wave >= B * K) return;
    const int b = wave / K;
    const int k = wave - b * K;

    const float* cptr = centroids + (size_t)(b * K + k) * 3;
    const float c0 = cptr[0], c1 = cptr[1], c2 = cptr[2];
    const float cc = (c0 * c0 + c1 * c1) + c2 * c2;

    const float* pbase = points + (size_t)b * N * 3;
    int* idxrow = idx_ws + (size_t)wave * NS;
    float* gpb = gp_out + ((size_t)b * 3 * K + k) * NS;  // + d*K*NS for dim d

    int count = 0;
    int idx0 = 0;  // first in-radius index (or 0 if none — matches order[0]=0)

    for (int base = 0; base < N; base += 64) {
        const int i = base + lane;
        const float p0 = pbase[i * 3 + 0];
        const float p1 = pbase[i * 3 + 1];
        const float p2 = pbase[i * 3 + 2];
        const float pp = (p0 * p0 + p1 * p1) + p2 * p2;
        const float cp = (c0 * p0 + c1 * p1) + c2 * p2;
        const float d2 = (cc + pp) - 2.0f * cp;
        const bool hit = d2 < RAD2;
        const unsigned long long m = __ballot(hit);
        if (hit) {
            const unsigned long long below = m & ((1ull << lane) - 1ull);
            const int pos = count + __popcll(below);
            if (pos < NS) {
                idxrow[pos] = i;
                gpb[0 * K * NS + pos] = (p0 - c0) * 4.0f;
                gpb[1 * K * NS + pos] = (p1 - c1) * 4.0f;
                gpb[2 * K * NS + pos] = (p2 - c2) * 4.0f;
            }
        }
        if (count == 0 && m != 0ull) idx0 = base + __builtin_ctzll(m);
        count += __popcll(m);
        if (count >= NS) break;  // wave-uniform
    }

    // Padding: slots [min(count,NS), NS) get idx0's point
    const int cnt = count < NS ? count : NS;
    if (lane >= cnt && lane < NS) {
        const float p0 = pbase[idx0 * 3 + 0];
        const float p1 = pbase[idx0 * 3 + 1];
        const float p2 = pbase[idx0 * 3 + 2];
        idxrow[lane] = idx0;
        gpb[0 * K * NS + lane] = (p0 - c0) * 4.0f;
        gpb[1 * K * NS + lane] = (p1 - c1) * 4.0f;
        gpb[2 * K * NS + lane] = (p2 - c2) * 4.0f;
    }
}

// ---------------------------------------------------------------------------
// Kernel B v2: one block per (b,c). Stage the 32 KB feature row in LDS once,
// then all K*NS gathers for this row are ds_read_b32 (random-bank ~2-3x
// aliasing, cheap) instead of 64B-line global transactions per 4B gather.
// HBM side: 16 MB feature reads (each row once) + 2 MB idx + 134 MB stores.
// ---------------------------------------------------------------------------
__global__ __launch_bounds__(1024) void gather_feats_lds(
    const float* __restrict__ features,  // (B, C, N)
    const int* __restrict__ idx_ws,      // (B, K, NS)
    float* __restrict__ nf_out)          // (B, C, K, NS)
{
    __shared__ float row[N];  // 32 KB
    const int bc = blockIdx.x;           // b*C + c
    const int t = threadIdx.x;

    // Stage: coalesced float4 loads, each row read exactly once per kernel
    {
        const float4* frow4 = reinterpret_cast<const float4*>(features + (size_t)bc * N);
        float4* row4 = reinterpret_cast<float4*>(row);
#pragma unroll
        for (int j = 0; j < 2; ++j)
            row4[t + j * 1024] = frow4[t + j * 1024];
    }
    __syncthreads();

    const int b = bc >> 6;               // C = 64
    const int* idxb = idx_ws + (size_t)b * K * NS;
    float* outb = nf_out + (size_t)bc * K * NS;

    // K*NS/4 = 16384 float4 groups; 1024 threads x 16 iterations, coalesced.
#pragma unroll
    for (int j = 0; j < 16; ++j) {
        const int g = j * 1024 + t;
        const int4 iv = *reinterpret_cast<const int4*>(idxb + (size_t)g * 4);
        float4 v;
        v.x = row[iv.x];
        v.y = row[iv.y];
        v.z = row[iv.z];
        v.w = row[iv.w];
        *reinterpret_cast<float4*>(outb + (size_t)g * 4) = v;
    }
}

extern "C" void kernel_launch(void* const* d_in, const int* in_sizes, int n_in,
                              void* d_out, int out_size, void* d_ws, size_t ws_size,
                              hipStream_t stream) {
    const float* points    = (const float*)d_in[0];
    const float* centroids = (const float*)d_in[1];
    const float* features  = (const float*)d_in[2];
    float* out = (float*)d_out;

    float* gp_out = out;                              // B*3*K*NS = 1,572,864
    float* nf_out = out + (size_t)B * 3 * K * NS;     // B*C*K*NS = 33,554,432
    int* idx_ws = (int*)d_ws;                         // needs B*K*NS*4 = 2 MB

    // Kernel A: one wave per centroid -> B*K waves, 4 waves/block
    const int waves = B * K;                          // 16384
    const int blocksA = waves / 4;                    // 4096 blocks of 256
    hipLaunchKernelGGL(ballquery_gp_kernel, dim3(blocksA), dim3(256), 0, stream,
                       points, centroids, gp_out, idx_ws);

    // Kernel B: one block per (b,c); 512 blocks = 2 blocks/CU, 32 KB LDS each
    hipLaunchKernelGGL(gather_feats_lds, dim3(B * C), dim3(1024), 0, stream,
                       features, idx_ws, nf_out);
}

// Round 5
// 56.804 us; speedup vs baseline: 1.3390x; 1.0749x over previous
//
#include <hip/hip_runtime.h>

// Problem constants (from reference)
constexpr int B = 8;
constexpr int N = 8192;
constexpr int K = 2048;
constexpr int C = 64;
constexpr int NS = 32;            // N_SAMPLE
#define RAD2 0.0625f              // RADIUS^2, exact in fp32

// Native vector types (required by __builtin_nontemporal_*; HIP_vector_type
// structs are rejected by the builtin)
typedef float  fx4 __attribute__((ext_vector_type(4)));
typedef int    ix4 __attribute__((ext_vector_type(4)));

// ---------------------------------------------------------------------------
// Kernel A: ball query (one wave per centroid) + grouped_pts output + idx to ws
// Exact reference arithmetic: d2 = (|c|^2 + |p|^2) - 2*c.p, fp32, contract off,
// same add order as numpy. Selection = first NS in-radius indices ascending
// (stable argsort semantics); pad with first hit (or 0).
// Software-pipelined point loads (prefetch i+1 before computing i) to break
// the load->ballot->break serial chain; 128-thread blocks for tail balance.
// Plain stores here (only ~6 MB total; nt reserved for kernel B's stream).
// ---------------------------------------------------------------------------
__global__ __launch_bounds__(128) void ballquery_gp_kernel(
    const float* __restrict__ points,     // (B, N, 3)
    const float* __restrict__ centroids,  // (B, K, 3)
    float* __restrict__ gp_out,           // (B, 3, K, NS)
    int* __restrict__ idx_ws)             // (B, K, NS)
{
#pragma clang fp contract(off)
    const int wave = (blockIdx.x * blockDim.x + threadIdx.x) >> 6;
    const int lane = threadIdx.x & 63;
    if (wave >= B * K) return;
    const int b = wave >> 11;            // K = 2048
    const int k = wave & (K - 1);

    const float* cptr = centroids + (size_t)(b * K + k) * 3;
    const float c0 = cptr[0], c1 = cptr[1], c2 = cptr[2];
    const float cc = (c0 * c0 + c1 * c1) + c2 * c2;

    const float* pbase = points + (size_t)b * N * 3;
    int* idxrow = idx_ws + (size_t)wave * NS;
    float* gpb = gp_out + ((size_t)b * 3 * K + k) * NS;  // + d*K*NS for dim d

    const unsigned long long below_mask = (lane == 63) ? ~0ull >> 1
                                                       : (1ull << lane) - 1ull;

    int count = 0;
    int idx0 = 0;

    // prefetched current-iteration point
    float q0 = pbase[lane * 3 + 0];
    float q1 = pbase[lane * 3 + 1];
    float q2 = pbase[lane * 3 + 2];

    for (int base = 0; base < N; base += 64) {
        // prefetch next iteration (wraps to 0 on last iter; value unused)
        const int nb = (base + 64 < N) ? (base + 64 + lane) : lane;
        const float n0 = pbase[nb * 3 + 0];
        const float n1 = pbase[nb * 3 + 1];
        const float n2 = pbase[nb * 3 + 2];

        const float pp = (q0 * q0 + q1 * q1) + q2 * q2;
        const float cp = (c0 * q0 + c1 * q1) + c2 * q2;
        const float d2 = (cc + pp) - 2.0f * cp;
        const bool hit = d2 < RAD2;
        const unsigned long long m = __ballot(hit);
        if (hit) {
            const int pos = count + __popcll(m & below_mask);
            if (pos < NS) {
                idxrow[pos] = base + lane;
                gpb[0 * K * NS + pos] = (q0 - c0) * 4.0f;
                gpb[1 * K * NS + pos] = (q1 - c1) * 4.0f;
                gpb[2 * K * NS + pos] = (q2 - c2) * 4.0f;
            }
        }
        if (count == 0 && m != 0ull) idx0 = base + __builtin_ctzll(m);
        count += __popcll(m);
        if (count >= NS) break;  // wave-uniform
        q0 = n0; q1 = n1; q2 = n2;
    }

    // Padding: slots [min(count,NS), NS) get idx0's point
    const int cnt = count < NS ? count : NS;
    if (lane >= cnt && lane < NS) {
        const float p0 = pbase[idx0 * 3 + 0];
        const float p1 = pbase[idx0 * 3 + 1];
        const float p2 = pbase[idx0 * 3 + 2];
        idxrow[lane] = idx0;
        gpb[0 * K * NS + lane] = (p0 - c0) * 4.0f;
        gpb[1 * K * NS + lane] = (p1 - c1) * 4.0f;
        gpb[2 * K * NS + lane] = (p2 - c2) * 4.0f;
    }
}

// ---------------------------------------------------------------------------
// Kernel B: one block per (b,c). Stage the 32 KB feature row in LDS once
// (nontemporal loads — each row read exactly once), then K*NS gathers as
// ds_read_b32. idx int4 prefetched one iteration ahead to break the
// idx-load -> ds_read -> store dependency chain. Nontemporal fx4 stores
// (output never re-read) keep idx/points resident in L2.
// ---------------------------------------------------------------------------
__global__ __launch_bounds__(1024) void gather_feats_lds(
    const float* __restrict__ features,  // (B, C, N)
    const int* __restrict__ idx_ws,      // (B, K, NS)
    float* __restrict__ nf_out)          // (B, C, K, NS)
{
    __shared__ float row[N];  // 32 KB
    const int bc = blockIdx.x;           // b*C + c
    const int t = threadIdx.x;

    {
        const fx4* frow4 = reinterpret_cast<const fx4*>(features + (size_t)bc * N);
        fx4* row4 = reinterpret_cast<fx4*>(row);
#pragma unroll
        for (int j = 0; j < 2; ++j)
            row4[t + j * 1024] = __builtin_nontemporal_load(&frow4[t + j * 1024]);
    }
    __syncthreads();

    const int b = bc >> 6;               // C = 64
    const int* idxb = idx_ws + (size_t)b * K * NS;
    float* outb = nf_out + (size_t)bc * K * NS;

    // K*NS/4 = 16384 int4 groups; 1024 threads x 16 iterations, coalesced.
    ix4 iv = *reinterpret_cast<const ix4*>(idxb + (size_t)t * 4);
#pragma unroll
    for (int j = 0; j < 16; ++j) {
        const int g = j * 1024 + t;
        ix4 ivn;
        if (j < 15)
            ivn = *reinterpret_cast<const ix4*>(idxb + (size_t)(g + 1024) * 4);
        fx4 v;
        v.x = row[iv.x];
        v.y = row[iv.y];
        v.z = row[iv.z];
        v.w = row[iv.w];
        __builtin_nontemporal_store(v, reinterpret_cast<fx4*>(outb + (size_t)g * 4));
        if (j < 15) iv = ivn;
    }
}

extern "C" void kernel_launch(void* const* d_in, const int* in_sizes, int n_in,
                              void* d_out, int out_size, void* d_ws, size_t ws_size,
                              hipStream_t stream) {
    const float* points    = (const float*)d_in[0];
    const float* centroids = (const float*)d_in[1];
    const float* features  = (const float*)d_in[2];
    float* out = (float*)d_out;

    float* gp_out = out;                              // B*3*K*NS = 1,572,864
    float* nf_out = out + (size_t)B * 3 * K * NS;     // B*C*K*NS = 33,554,432
    int* idx_ws = (int*)d_ws;                         // needs B*K*NS*4 = 2 MB

    // Kernel A: one wave per centroid -> B*K waves, 2 waves/block
    const int waves = B * K;                          // 16384
    hipLaunchKernelGGL(ballquery_gp_kernel, dim3(waves / 2), dim3(128), 0, stream,
                       points, centroids, gp_out, idx_ws);

    // Kernel B: one block per (b,c); 512 blocks = 2 blocks/CU, 32 KB LDS each
    hipLaunchKernelGGL(gather_feats_lds, dim3(B * C), dim3(1024), 0, stream,
                       features, idx_ws, nf_out);
}